// Round 17
// baseline (64.767 us; speedup 1.0000x reference)
//
#include <hip/hip_runtime.h>
#include <hip/hip_bf16.h>

// Self-attention, fused QKV: x[4,2048,1024] f32, Wq/Wk/Wv[1024,64] f32 -> out[4,2048,64] f32
// bf16 MFMA (16x16x32), fp32 accumulation.
//   K1: wtrans  -- W -> Wt bf16 [192][1024], LDS tile-transpose.
//   K2: qkv_proj -- merged-N gload_lds pipeline: 256 blocks x 8 waves, M=32 x N=192,
//       BK=64, 3-buffer counted-vmcnt(4). x staged ONCE from HBM (was 2x).
//   K3: attn16  -- flash attn, split-KV x16 (1024 blocks, 8 waves x 128 keys),
//       partials to d_ws; T1 swizzle; setprio on MFMA clusters.
//   K4: attn_combine -- deterministic 2-way merge of the kv-halves.
//   Fallback: if ws_size < needed, r15 attn (split x8, direct out).

typedef __attribute__((ext_vector_type(8))) short bf16x8;
typedef __attribute__((ext_vector_type(4))) float f32x4;
typedef __attribute__((ext_vector_type(4))) unsigned short u16x4;

#define QSCALE 0.1803368801111832f   // 0.125 * log2(e); logits land in exp2 domain

__device__ __forceinline__ short f2bf(float f) {
    union { float f; unsigned u; } v; v.f = f;
    unsigned r = v.u + 0x7FFF + ((v.u >> 16) & 1);   // round-to-nearest-even
    return (short)(r >> 16);
}

__device__ __forceinline__ void gload16(const void* src, void* dst) {
    __builtin_amdgcn_global_load_lds(
        (const __attribute__((address_space(1))) unsigned int*)src,
        (__attribute__((address_space(3))) unsigned int*)dst, 16, 0, 0);
}

// ---------------- K1: weight transpose + bf16 convert (coalesced) ----------------
__global__ __launch_bounds__(256) void wtrans(const float* __restrict__ Wq,
                                              const float* __restrict__ Wk,
                                              const float* __restrict__ Wv,
                                              short* __restrict__ Wt) {
    __shared__ short lds[64][66];
    int warr = blockIdx.x / 16;
    int d0 = (blockIdx.x % 16) * 64;
    const float* W = (warr == 0) ? Wq : (warr == 1) ? Wk : Wv;
    int rg = threadIdx.x >> 6;
    int c  = threadIdx.x & 63;
    #pragma unroll
    for (int p = 0; p < 16; ++p) {
        int d = p * 4 + rg;
        lds[d][c] = f2bf(W[(d0 + d) * 64 + c]);
    }
    __syncthreads();
    #pragma unroll
    for (int p = 0; p < 16; ++p) {
        int n = p * 4 + rg;
        Wt[(warr * 64 + n) * 1024 + d0 + c] = lds[c][n];
    }
}

// ---------------- K2: QKV projection, merged-N counted-vmcnt pipeline ----------------
// grid 256 blocks x 512 thr (8 waves). Tile M=32 x N=192, BK=64 (16 steps).
// Buffer (32KB): A = 32 rows x 256B (chunks 0..7); B = 192 rows x 128B (chunks 0..23).
// Wave wid stages A chunk wid + B chunks {wid, wid+8, wid+16} = 4 gload16/thread/step.
// Swizzle rule #21: linear LDS dest + inverse-swizzled source + swizzled ds_read.
__global__ __launch_bounds__(512) void qkv_proj(const float* __restrict__ x,
                                                const short* __restrict__ Wt,
                                                short* __restrict__ Q,
                                                short* __restrict__ K,
                                                short* __restrict__ Vt) {
    __shared__ char stage_lds[3][32768];
    __shared__ short Vlds[32][72];

    int tid = threadIdx.x;
    int wid = tid >> 6, lane = tid & 63;
    int l15 = lane & 15, lg = lane >> 4;
    int wr = wid >> 2, wn = wid & 3;
    // T1 chunked swizzle (256 = 8 XCDs x 32)
    int logical = (blockIdx.x & 7) * 32 + (blockIdx.x >> 3);
    int mbase = logical * 32;

    // A source (j=0): chunk=wid (rows 4*wid..+3), 16B slot per lane
    int a_soff;
    {
        int row = wid * 4 + (lane >> 4);
        int slot16 = lane & 15;
        int s32 = slot16 >> 1, h16 = slot16 & 1;
        int s32s = s32 ^ (row & 7);
        a_soff = (mbase + row) * 1024 + s32s * 8 + h16 * 4;   // float offset
    }
    // B sources (j=0..2): chunk cb = wid + j*8 (rows 8*cb..+7)
    int b_soff[3];
    #pragma unroll
    for (int j = 0; j < 3; ++j) {
        int cb = wid + j * 8;
        int row = cb * 8 + (lane >> 3);
        int slot = lane & 7;
        int ss = slot ^ (row & 7);
        b_soff[j] = row * 1024 + ss * 8;                      // short offset
    }

    f32x4 acc[3];
    #pragma unroll
    for (int f = 0; f < 3; ++f) acc[f] = (f32x4){0.f, 0.f, 0.f, 0.f};

    char* B0 = &stage_lds[0][0];
    char* B1 = &stage_lds[1][0];
    char* B2 = &stage_lds[2][0];

#define STAGE(step, base)                                                        \
    {                                                                            \
        int k0_ = (step) * 64;                                                   \
        gload16(x + a_soff + k0_, (base) + wid * 1024);                          \
        _Pragma("unroll")                                                        \
        for (int j = 0; j < 3; ++j)                                              \
            gload16(Wt + b_soff[j] + k0_, (base) + 8192 + (wid + j * 8) * 1024); \
    }

    STAGE(0, B0);
    STAGE(1, B1);
    asm volatile("s_waitcnt vmcnt(4)" ::: "memory");
    __builtin_amdgcn_s_barrier();
    __builtin_amdgcn_sched_barrier(0);

    for (int t = 0; t < 16; ++t) {
        int cm = t % 3;
        char* cbuf = (cm == 0) ? B0 : (cm == 1) ? B1 : B2;
        if (t + 2 < 16) {
            int nm = (t + 2) % 3;
            char* nbuf = (nm == 0) ? B0 : (nm == 1) ? B1 : B2;
            STAGE(t + 2, nbuf);
        }
        const char* Ab = cbuf;
        const char* Bb = cbuf + 8192;
        int arow = wr * 16 + l15;
        __builtin_amdgcn_s_setprio(1);
        #pragma unroll
        for (int h = 0; h < 2; ++h) {
            int s32s = (h * 4 + lg) ^ (arow & 7);
            const float4* ap = (const float4*)(Ab + arow * 256 + s32s * 32);
            float4 f0 = ap[0];
            float4 f1 = ap[1];
            bf16x8 a;
            a[0] = f2bf(f0.x); a[1] = f2bf(f0.y); a[2] = f2bf(f0.z); a[3] = f2bf(f0.w);
            a[4] = f2bf(f1.x); a[5] = f2bf(f1.y); a[6] = f2bf(f1.z); a[7] = f2bf(f1.w);
            #pragma unroll
            for (int f = 0; f < 3; ++f) {
                int brow = (wn * 3 + f) * 16 + l15;     // 0..191 across waves
                int ss = (h * 4 + lg) ^ (brow & 7);
                bf16x8 b = *(const bf16x8*)(Bb + brow * 128 + ss * 16);
                acc[f] = __builtin_amdgcn_mfma_f32_16x16x32_bf16(a, b, acc[f], 0, 0, 0);
            }
        }
        __builtin_amdgcn_s_setprio(0);
        if (t < 15) {
            if (t == 14) {
                asm volatile("s_waitcnt vmcnt(0)" ::: "memory");
            } else {
                asm volatile("s_waitcnt vmcnt(4)" ::: "memory");
            }
            __builtin_amdgcn_s_barrier();
            __builtin_amdgcn_sched_barrier(0);
        }
    }
#undef STAGE

    // epilogue. n = (wn*3+f)*16 + l15 (0..191); m = mbase + wr*16 + lg*4 + r.
    #pragma unroll
    for (int f = 0; f < 3; ++f) {
        int n = (wn * 3 + f) * 16 + l15;
        #pragma unroll
        for (int r = 0; r < 4; ++r) {
            int ml = wr * 16 + lg * 4 + r;
            int m = mbase + ml;
            float v = acc[f][r];
            if (n < 64) {
                Q[m * 64 + n] = f2bf(v * QSCALE);
            } else if (n < 128) {
                K[m * 64 + (n - 64)] = f2bf(v);
            } else {
                Vlds[ml][n - 128] = f2bf(v);
            }
        }
    }
    __syncthreads();
    // Vt[(b*64+dk)*2048 + mbase + m]: 2048 shorts, 512 thr x 1 u16x4
    {
        int dk = tid >> 3;            // 0..63
        int m0 = (tid & 7) * 4;       // 0..28
        int b_ = mbase >> 11;
        int s_ = mbase & 2047;
        u16x4 v;
        #pragma unroll
        for (int i = 0; i < 4; ++i) v[i] = (unsigned short)Vlds[m0 + i][dk];
        *(u16x4*)&Vt[(b_ * 64 + dk) * 2048 + s_ + m0] = v;
    }
}

// ---------------- K3a: flash attention, split-KV x16, partials to ws ----------------
__global__ __launch_bounds__(512) void attn16(const short* __restrict__ Q,
                                              const short* __restrict__ K,
                                              const short* __restrict__ Vt,
                                              float* __restrict__ P_m,
                                              float* __restrict__ P_l,
                                              float* __restrict__ P_acc) {
    __shared__ float accw[8][16][68];
    __shared__ short P_lds[8][16][72];
    __shared__ float Mw[8][16];
    __shared__ float Lw[8][16];
    __shared__ float Ltot[16];
    __shared__ float Mtot_s[16];

    int tid = threadIdx.x, wid = tid >> 6, lane = tid & 63;
    int l15 = lane & 15, lg = lane >> 4;
    int logical = (blockIdx.x & 7) * 128 + (blockIdx.x >> 3);
    int b_ = logical >> 8;
    int qt = (logical >> 1) & 127;
    int half = logical & 1;
    int q0 = qt * 16;
    const short* Kb = K + b_ * 2048 * 64;
    const short* Vb = Vt + b_ * 64 * 2048;

    const short* Qp = Q + (b_ * 2048 + q0 + l15) * 64 + lg * 8;
    bf16x8 bq0 = *(const bf16x8*)Qp;
    bf16x8 bq1 = *(const bf16x8*)(Qp + 32);

    f32x4 acc[4];
    #pragma unroll
    for (int t = 0; t < 4; ++t) acc[t] = (f32x4){0.f, 0.f, 0.f, 0.f};
    float m_run = -INFINITY, l_run = 0.f;

    int kv0 = half * 1024 + wid * 128;
    for (int kv = kv0; kv < kv0 + 128; kv += 64) {
        f32x4 s[4];
        __builtin_amdgcn_s_setprio(1);
        #pragma unroll
        for (int kt = 0; kt < 4; ++kt) {
            const short* Kp = Kb + (kv + kt * 16 + l15) * 64 + lg * 8;
            bf16x8 ak0 = *(const bf16x8*)Kp;
            bf16x8 ak1 = *(const bf16x8*)(Kp + 32);
            f32x4 z = (f32x4){0.f, 0.f, 0.f, 0.f};
            z = __builtin_amdgcn_mfma_f32_16x16x32_bf16(ak0, bq0, z, 0, 0, 0);
            s[kt] = __builtin_amdgcn_mfma_f32_16x16x32_bf16(ak1, bq1, z, 0, 0, 0);
        }
        __builtin_amdgcn_s_setprio(0);

        float m01 = fmaxf(fmaxf(s[0][0], s[0][1]), fmaxf(s[0][2], s[0][3]));
        float m23 = fmaxf(fmaxf(s[1][0], s[1][1]), fmaxf(s[1][2], s[1][3]));
        float m45 = fmaxf(fmaxf(s[2][0], s[2][1]), fmaxf(s[2][2], s[2][3]));
        float m67 = fmaxf(fmaxf(s[3][0], s[3][1]), fmaxf(s[3][2], s[3][3]));
        float mt = fmaxf(fmaxf(m01, m23), fmaxf(m45, m67));
        mt = fmaxf(mt, __shfl_xor(mt, 16));
        mt = fmaxf(mt, __shfl_xor(mt, 32));
        float mn = fmaxf(m_run, mt);
        float c = exp2f(m_run - mn);
        m_run = mn;
        float rs = 0.f;
        #pragma unroll
        for (int kt = 0; kt < 4; ++kt)
            #pragma unroll
            for (int r = 0; r < 4; ++r) {
                float p = exp2f(s[kt][r] - mn);
                s[kt][r] = p;
                rs += p;
            }
        rs += __shfl_xor(rs, 16);
        rs += __shfl_xor(rs, 32);
        l_run = l_run * c + rs;
        #pragma unroll
        for (int t = 0; t < 4; ++t)
            #pragma unroll
            for (int r = 0; r < 4; ++r) acc[t][r] *= c;

        #pragma unroll
        for (int kt = 0; kt < 4; ++kt) {
            u16x4 h;
            h[0] = (unsigned short)f2bf(s[kt][0]);
            h[1] = (unsigned short)f2bf(s[kt][1]);
            h[2] = (unsigned short)f2bf(s[kt][2]);
            h[3] = (unsigned short)f2bf(s[kt][3]);
            *(u16x4*)&P_lds[wid][l15][kt * 16 + lg * 4] = h;
        }

        __builtin_amdgcn_s_setprio(1);
        #pragma unroll
        for (int ps = 0; ps < 2; ++ps) {
            bf16x8 bp = *(const bf16x8*)&P_lds[wid][l15][ps * 32 + lg * 8];
            #pragma unroll
            for (int t = 0; t < 4; ++t) {
                const short* Vp = Vb + (t * 16 + l15) * 2048 + kv + ps * 32 + lg * 8;
                bf16x8 av = *(const bf16x8*)Vp;
                acc[t] = __builtin_amdgcn_mfma_f32_16x16x32_bf16(av, bp, acc[t], 0, 0, 0);
            }
        }
        __builtin_amdgcn_s_setprio(0);
    }

    if (lg == 0) {
        Mw[wid][l15] = m_run;
        Lw[wid][l15] = l_run;
    }
    __syncthreads();

    float mtot = Mw[0][l15];
    #pragma unroll
    for (int w = 1; w < 8; ++w) mtot = fmaxf(mtot, Mw[w][l15]);
    float fac = exp2f(m_run - mtot);
    #pragma unroll
    for (int t = 0; t < 4; ++t) {
        f32x4 v = acc[t];
        v[0] *= fac; v[1] *= fac; v[2] *= fac; v[3] *= fac;
        *(f32x4*)&accw[wid][l15][t * 16 + lg * 4] = v;
    }

    if (wid == 0 && lg == 0) {
        float L = 0.f;
        #pragma unroll
        for (int w = 0; w < 8; ++w)
            L += Lw[w][l15] * exp2f(Mw[w][l15] - mtot);
        Ltot[l15] = L;
        Mtot_s[l15] = mtot;
    }
    __syncthreads();

    int pidx = logical;
    #pragma unroll
    for (int j = 0; j < 2; ++j) {
        int o = tid + j * 512;
        int row = o >> 6, col = o & 63;
        float ssum = 0.f;
        #pragma unroll
        for (int w = 0; w < 8; ++w) ssum += accw[w][row][col];
        P_acc[(pidx * 16 + row) * 64 + col] = ssum;
    }
    if (tid < 16) {
        P_m[pidx * 16 + tid] = Mtot_s[tid];
        P_l[pidx * 16 + tid] = Ltot[tid];
    }
}

// ---------------- K4: combine the two kv-halves ----------------
__global__ __launch_bounds__(256) void attn_combine(const float* __restrict__ P_m,
                                                    const float* __restrict__ P_l,
                                                    const float* __restrict__ P_acc,
                                                    float* __restrict__ out) {
    int pair = blockIdx.x;
    int b_ = pair >> 7, qt = pair & 127;
    int p0 = pair * 2, p1 = pair * 2 + 1;
    #pragma unroll
    for (int j = 0; j < 4; ++j) {
        int o = threadIdx.x + j * 256;
        int row = o >> 6, col = o & 63;
        float m0 = P_m[p0 * 16 + row], m1 = P_m[p1 * 16 + row];
        float l0 = P_l[p0 * 16 + row], l1 = P_l[p1 * 16 + row];
        float m = fmaxf(m0, m1);
        float f0 = exp2f(m0 - m), f1 = exp2f(m1 - m);
        float L = l0 * f0 + l1 * f1;
        float a = P_acc[(p0 * 16 + row) * 64 + col] * f0
                + P_acc[(p1 * 16 + row) * 64 + col] * f1;
        out[(b_ * 2048 + qt * 16 + row) * 64 + col] = a / L;
    }
}

// ---------------- K3b: fallback attn (r15, split x8, direct out) ----------------
__global__ __launch_bounds__(512) void attn(const short* __restrict__ Q,
                                            const short* __restrict__ K,
                                            const short* __restrict__ Vt,
                                            float* __restrict__ out) {
    __shared__ float accw[8][16][68];
    __shared__ short P_lds[8][16][72];
    __shared__ float Mw[8][16];
    __shared__ float Lw[8][16];
    __shared__ float Ltot[16];

    int tid = threadIdx.x, wid = tid >> 6, lane = tid & 63;
    int l15 = lane & 15, lg = lane >> 4;
    int logical = (blockIdx.x & 7) * 64 + (blockIdx.x >> 3);
    int b_ = logical >> 7;
    int q0 = (logical & 127) * 16;
    const short* Kb = K + b_ * 2048 * 64;
    const short* Vb = Vt + b_ * 64 * 2048;

    const short* Qp = Q + (b_ * 2048 + q0 + l15) * 64 + lg * 8;
    bf16x8 bq0 = *(const bf16x8*)Qp;
    bf16x8 bq1 = *(const bf16x8*)(Qp + 32);

    f32x4 acc[4];
    #pragma unroll
    for (int t = 0; t < 4; ++t) acc[t] = (f32x4){0.f, 0.f, 0.f, 0.f};
    float m_run = -INFINITY, l_run = 0.f;

    int kv0 = wid * 256;
    for (int kv = kv0; kv < kv0 + 256; kv += 64) {
        f32x4 s[4];
        __builtin_amdgcn_s_setprio(1);
        #pragma unroll
        for (int kt = 0; kt < 4; ++kt) {
            const short* Kp = Kb + (kv + kt * 16 + l15) * 64 + lg * 8;
            bf16x8 ak0 = *(const bf16x8*)Kp;
            bf16x8 ak1 = *(const bf16x8*)(Kp + 32);
            f32x4 z = (f32x4){0.f, 0.f, 0.f, 0.f};
            z = __builtin_amdgcn_mfma_f32_16x16x32_bf16(ak0, bq0, z, 0, 0, 0);
            s[kt] = __builtin_amdgcn_mfma_f32_16x16x32_bf16(ak1, bq1, z, 0, 0, 0);
        }
        __builtin_amdgcn_s_setprio(0);

        float m01 = fmaxf(fmaxf(s[0][0], s[0][1]), fmaxf(s[0][2], s[0][3]));
        float m23 = fmaxf(fmaxf(s[1][0], s[1][1]), fmaxf(s[1][2], s[1][3]));
        float m45 = fmaxf(fmaxf(s[2][0], s[2][1]), fmaxf(s[2][2], s[2][3]));
        float m67 = fmaxf(fmaxf(s[3][0], s[3][1]), fmaxf(s[3][2], s[3][3]));
        float mt = fmaxf(fmaxf(m01, m23), fmaxf(m45, m67));
        mt = fmaxf(mt, __shfl_xor(mt, 16));
        mt = fmaxf(mt, __shfl_xor(mt, 32));
        float mn = fmaxf(m_run, mt);
        float c = exp2f(m_run - mn);
        m_run = mn;
        float rs = 0.f;
        #pragma unroll
        for (int kt = 0; kt < 4; ++kt)
            #pragma unroll
            for (int r = 0; r < 4; ++r) {
                float p = exp2f(s[kt][r] - mn);
                s[kt][r] = p;
                rs += p;
            }
        rs += __shfl_xor(rs, 16);
        rs += __shfl_xor(rs, 32);
        l_run = l_run * c + rs;
        #pragma unroll
        for (int t = 0; t < 4; ++t)
            #pragma unroll
            for (int r = 0; r < 4; ++r) acc[t][r] *= c;

        #pragma unroll
        for (int kt = 0; kt < 4; ++kt) {
            u16x4 h;
            h[0] = (unsigned short)f2bf(s[kt][0]);
            h[1] = (unsigned short)f2bf(s[kt][1]);
            h[2] = (unsigned short)f2bf(s[kt][2]);
            h[3] = (unsigned short)f2bf(s[kt][3]);
            *(u16x4*)&P_lds[wid][l15][kt * 16 + lg * 4] = h;
        }

        __builtin_amdgcn_s_setprio(1);
        #pragma unroll
        for (int ps = 0; ps < 2; ++ps) {
            bf16x8 bp = *(const bf16x8*)&P_lds[wid][l15][ps * 32 + lg * 8];
            #pragma unroll
            for (int t = 0; t < 4; ++t) {
                const short* Vp = Vb + (t * 16 + l15) * 2048 + kv + ps * 32 + lg * 8;
                bf16x8 av = *(const bf16x8*)Vp;
                acc[t] = __builtin_amdgcn_mfma_f32_16x16x32_bf16(av, bp, acc[t], 0, 0, 0);
            }
        }
        __builtin_amdgcn_s_setprio(0);
    }

    if (lg == 0) {
        Mw[wid][l15] = m_run;
        Lw[wid][l15] = l_run;
    }
    __syncthreads();

    float mtot = Mw[0][l15];
    #pragma unroll
    for (int w = 1; w < 8; ++w) mtot = fmaxf(mtot, Mw[w][l15]);
    float fac = exp2f(m_run - mtot);
    #pragma unroll
    for (int t = 0; t < 4; ++t) {
        f32x4 v = acc[t];
        v[0] *= fac; v[1] *= fac; v[2] *= fac; v[3] *= fac;
        *(f32x4*)&accw[wid][l15][t * 16 + lg * 4] = v;
    }

    if (wid == 0 && lg == 0) {
        float L = 0.f;
        #pragma unroll
        for (int w = 0; w < 8; ++w)
            L += Lw[w][l15] * exp2f(Mw[w][l15] - mtot);
        Ltot[l15] = L;
    }
    __syncthreads();

    #pragma unroll
    for (int j = 0; j < 2; ++j) {
        int o = tid + j * 512;
        int row = o >> 6, col = o & 63;
        float ssum = 0.f;
        #pragma unroll
        for (int w = 0; w < 8; ++w) ssum += accw[w][row][col];
        out[(b_ * 2048 + q0 + row) * 64 + col] = ssum / Ltot[row];
    }
}

extern "C" void kernel_launch(void* const* d_in, const int* in_sizes, int n_in,
                              void* d_out, int out_size, void* d_ws, size_t ws_size,
                              hipStream_t stream) {
    const float* x  = (const float*)d_in[0];
    const float* Wq = (const float*)d_in[1];
    const float* Wk = (const float*)d_in[2];
    const float* Wv = (const float*)d_in[3];
    float* out = (float*)d_out;

    char* ws = (char*)d_ws;
    short* Wt = (short*)ws;                              // 393216 B
    short* Q  = (short*)(ws + 393216);                   // 1048576 B
    short* K  = (short*)(ws + 393216 + 1048576);         // 1048576 B
    short* Vt = (short*)(ws + 393216 + 2 * 1048576);     // 1048576 B  (3538944 total)
    float* P_m   = (float*)(ws + 3538944);               // 65536 B
    float* P_l   = (float*)(ws + 3538944 + 65536);       // 65536 B
    float* P_acc = (float*)(ws + 3538944 + 131072);      // 4194304 B
    const size_t WS_NEEDED = 3538944 + 131072 + 4194304; // 7864320

    hipLaunchKernelGGL(wtrans,   dim3(48),  dim3(256), 0, stream, Wq, Wk, Wv, Wt);
    hipLaunchKernelGGL(qkv_proj, dim3(256), dim3(512), 0, stream, x, Wt, Q, K, Vt);
    if (ws_size >= WS_NEEDED) {
        hipLaunchKernelGGL(attn16,       dim3(1024), dim3(512), 0, stream, Q, K, Vt, P_m, P_l, P_acc);
        hipLaunchKernelGGL(attn_combine, dim3(512),  dim3(256), 0, stream, P_m, P_l, P_acc, out);
    } else {
        hipLaunchKernelGGL(attn, dim3(512), dim3(512), 0, stream, Q, K, Vt, out);
    }
}

// Round 18
// 62.014 us; speedup vs baseline: 1.0444x; 1.0444x over previous
//
#include <hip/hip_runtime.h>
#include <hip/hip_bf16.h>

// Self-attention, fused QKV: x[4,2048,1024] f32, Wq/Wk/Wv[1024,64] f32 -> out[4,2048,64] f32
// bf16 MFMA (16x16x32), fp32 accumulation.
//   K1: wtrans  -- W -> Wt bf16 [192][1024], LDS tile-transpose.
//   K2: qkv_proj -- r16 proven: 512 blocks x 4 waves, M=32 x N=96, gload_lds
//       3-buffer counted-vmcnt(5) pipeline, T1 XCD swizzle (N-half pairs share L2).
//   K3: attn16  -- flash attn, split-KV x16, partials to d_ws; T1 swizzle; setprio;
//       NEW: T13 defer-max (skip rescale when tile max within 8 of running max).
//   K4: attn_combine -- deterministic 2-way merge of the kv-halves.
//   Fallback: r15-style attn (split x8, direct out) with T13 too.

typedef __attribute__((ext_vector_type(8))) short bf16x8;
typedef __attribute__((ext_vector_type(4))) float f32x4;
typedef __attribute__((ext_vector_type(4))) unsigned short u16x4;

#define QSCALE 0.1803368801111832f   // 0.125 * log2(e); logits land in exp2 domain

__device__ __forceinline__ short f2bf(float f) {
    union { float f; unsigned u; } v; v.f = f;
    unsigned r = v.u + 0x7FFF + ((v.u >> 16) & 1);   // round-to-nearest-even
    return (short)(r >> 16);
}

__device__ __forceinline__ void gload16(const void* src, void* dst) {
    __builtin_amdgcn_global_load_lds(
        (const __attribute__((address_space(1))) unsigned int*)src,
        (__attribute__((address_space(3))) unsigned int*)dst, 16, 0, 0);
}

// ---------------- K1: weight transpose + bf16 convert (coalesced) ----------------
__global__ __launch_bounds__(256) void wtrans(const float* __restrict__ Wq,
                                              const float* __restrict__ Wk,
                                              const float* __restrict__ Wv,
                                              short* __restrict__ Wt) {
    __shared__ short lds[64][66];
    int warr = blockIdx.x / 16;
    int d0 = (blockIdx.x % 16) * 64;
    const float* W = (warr == 0) ? Wq : (warr == 1) ? Wk : Wv;
    int rg = threadIdx.x >> 6;
    int c  = threadIdx.x & 63;
    #pragma unroll
    for (int p = 0; p < 16; ++p) {
        int d = p * 4 + rg;
        lds[d][c] = f2bf(W[(d0 + d) * 64 + c]);
    }
    __syncthreads();
    #pragma unroll
    for (int p = 0; p < 16; ++p) {
        int n = p * 4 + rg;
        Wt[(warr * 64 + n) * 1024 + d0 + c] = lds[c][n];
    }
}

// ---------------- K2: QKV projection (r16 pipeline + T1 swizzle) ----------------
__global__ __launch_bounds__(256) void qkv_proj(const float* __restrict__ x,
                                                const short* __restrict__ Wt,
                                                short* __restrict__ Q,
                                                short* __restrict__ K,
                                                short* __restrict__ Vt) {
    __shared__ char stage_lds[3][20480];
    __shared__ short Vlds[32][72];

    int tid = threadIdx.x;
    int wid = tid >> 6, lane = tid & 63;
    int l15 = lane & 15, lg = lane >> 4;
    int wr = wid >> 1, wn = wid & 1;
    // T1 chunked swizzle (512 = 8 XCDs x 64): pairs (2i,2i+1) -> same XCD L2
    int logical = (blockIdx.x & 7) * 64 + (blockIdx.x >> 3);
    int mbase = (logical >> 1) * 32;
    int nbase = (logical & 1) * 96;

    int a_soff[2];
    #pragma unroll
    for (int j = 0; j < 2; ++j) {
        int chunk = wid + j * 4;
        int row = chunk * 4 + (lane >> 4);
        int slot16 = lane & 15;
        int s32 = slot16 >> 1, h16 = slot16 & 1;
        int s32s = s32 ^ (row & 7);
        a_soff[j] = (mbase + row) * 1024 + s32s * 8 + h16 * 4;   // float offset
    }
    int b_soff[3];
    #pragma unroll
    for (int j = 0; j < 3; ++j) {
        int cb = wid + j * 4;
        int row = cb * 8 + (lane >> 3);
        int slot = lane & 7;
        int ss = slot ^ (row & 7);
        b_soff[j] = (nbase + row) * 1024 + ss * 8;               // short offset
    }

    f32x4 acc[3];
    #pragma unroll
    for (int f = 0; f < 3; ++f) acc[f] = (f32x4){0.f, 0.f, 0.f, 0.f};

    char* B0 = &stage_lds[0][0];
    char* B1 = &stage_lds[1][0];
    char* B2 = &stage_lds[2][0];

#define STAGE(step, base)                                                    \
    {                                                                        \
        int k0_ = (step) * 64;                                               \
        _Pragma("unroll")                                                    \
        for (int j = 0; j < 2; ++j)                                          \
            gload16(x + a_soff[j] + k0_, (base) + (wid + j * 4) * 1024);     \
        _Pragma("unroll")                                                    \
        for (int j = 0; j < 3; ++j)                                          \
            gload16(Wt + b_soff[j] + k0_, (base) + 8192 + (wid + j * 4) * 1024); \
    }

    STAGE(0, B0);
    STAGE(1, B1);
    asm volatile("s_waitcnt vmcnt(5)" ::: "memory");
    __builtin_amdgcn_s_barrier();
    __builtin_amdgcn_sched_barrier(0);

    for (int t = 0; t < 16; ++t) {
        int cm = t % 3;
        char* cbuf = (cm == 0) ? B0 : (cm == 1) ? B1 : B2;
        if (t + 2 < 16) {
            int nm = (t + 2) % 3;
            char* nbuf = (nm == 0) ? B0 : (nm == 1) ? B1 : B2;
            STAGE(t + 2, nbuf);
        }
        const char* Ab = cbuf;
        const char* Bb = cbuf + 8192;
        int arow = wr * 16 + l15;
        __builtin_amdgcn_s_setprio(1);
        #pragma unroll
        for (int h = 0; h < 2; ++h) {
            int s32s = (h * 4 + lg) ^ (arow & 7);
            const float4* ap = (const float4*)(Ab + arow * 256 + s32s * 32);
            float4 f0 = ap[0];
            float4 f1 = ap[1];
            bf16x8 a;
            a[0] = f2bf(f0.x); a[1] = f2bf(f0.y); a[2] = f2bf(f0.z); a[3] = f2bf(f0.w);
            a[4] = f2bf(f1.x); a[5] = f2bf(f1.y); a[6] = f2bf(f1.z); a[7] = f2bf(f1.w);
            #pragma unroll
            for (int f = 0; f < 3; ++f) {
                int brow = (wn * 3 + f) * 16 + l15;
                int ss = (h * 4 + lg) ^ (brow & 7);
                bf16x8 b = *(const bf16x8*)(Bb + brow * 128 + ss * 16);
                acc[f] = __builtin_amdgcn_mfma_f32_16x16x32_bf16(a, b, acc[f], 0, 0, 0);
            }
        }
        __builtin_amdgcn_s_setprio(0);
        if (t < 15) {
            if (t == 14) {
                asm volatile("s_waitcnt vmcnt(0)" ::: "memory");
            } else {
                asm volatile("s_waitcnt vmcnt(5)" ::: "memory");
            }
            __builtin_amdgcn_s_barrier();
            __builtin_amdgcn_sched_barrier(0);
        }
    }
#undef STAGE

    #pragma unroll
    for (int f = 0; f < 3; ++f) {
        int n = nbase + (wn * 3 + f) * 16 + l15;
        #pragma unroll
        for (int r = 0; r < 4; ++r) {
            int ml = wr * 16 + lg * 4 + r;
            int m = mbase + ml;
            float v = acc[f][r];
            if (n < 64) {
                Q[m * 64 + n] = f2bf(v * QSCALE);
            } else if (n < 128) {
                K[m * 64 + (n - 64)] = f2bf(v);
            } else {
                Vlds[ml][n - 128] = f2bf(v);
            }
        }
    }
    if (nbase == 96) {
        __syncthreads();
        int dk = tid >> 2;
        int m0 = (tid & 3) * 8;
        int b_ = mbase >> 11;
        int s_ = mbase & 2047;
        #pragma unroll
        for (int j = 0; j < 2; ++j) {
            u16x4 v;
            #pragma unroll
            for (int i = 0; i < 4; ++i) v[i] = (unsigned short)Vlds[m0 + j * 4 + i][dk];
            *(u16x4*)&Vt[(b_ * 64 + dk) * 2048 + s_ + m0 + j * 4] = v;
        }
    }
}

// ---------------- K3a: flash attention, split-KV x16, T13 defer-max ----------------
__global__ __launch_bounds__(512) void attn16(const short* __restrict__ Q,
                                              const short* __restrict__ K,
                                              const short* __restrict__ Vt,
                                              float* __restrict__ P_m,
                                              float* __restrict__ P_l,
                                              float* __restrict__ P_acc) {
    __shared__ float accw[8][16][68];
    __shared__ short P_lds[8][16][72];
    __shared__ float Mw[8][16];
    __shared__ float Lw[8][16];
    __shared__ float Ltot[16];
    __shared__ float Mtot_s[16];

    int tid = threadIdx.x, wid = tid >> 6, lane = tid & 63;
    int l15 = lane & 15, lg = lane >> 4;
    int logical = (blockIdx.x & 7) * 128 + (blockIdx.x >> 3);
    int b_ = logical >> 8;
    int qt = (logical >> 1) & 127;
    int half = logical & 1;
    int q0 = qt * 16;
    const short* Kb = K + b_ * 2048 * 64;
    const short* Vb = Vt + b_ * 64 * 2048;

    const short* Qp = Q + (b_ * 2048 + q0 + l15) * 64 + lg * 8;
    bf16x8 bq0 = *(const bf16x8*)Qp;
    bf16x8 bq1 = *(const bf16x8*)(Qp + 32);

    f32x4 acc[4];
    #pragma unroll
    for (int t = 0; t < 4; ++t) acc[t] = (f32x4){0.f, 0.f, 0.f, 0.f};
    float m_run = -INFINITY, l_run = 0.f;

    int kv0 = half * 1024 + wid * 128;
    for (int kv = kv0; kv < kv0 + 128; kv += 64) {
        f32x4 s[4];
        __builtin_amdgcn_s_setprio(1);
        #pragma unroll
        for (int kt = 0; kt < 4; ++kt) {
            const short* Kp = Kb + (kv + kt * 16 + l15) * 64 + lg * 8;
            bf16x8 ak0 = *(const bf16x8*)Kp;
            bf16x8 ak1 = *(const bf16x8*)(Kp + 32);
            f32x4 z = (f32x4){0.f, 0.f, 0.f, 0.f};
            z = __builtin_amdgcn_mfma_f32_16x16x32_bf16(ak0, bq0, z, 0, 0, 0);
            s[kt] = __builtin_amdgcn_mfma_f32_16x16x32_bf16(ak1, bq1, z, 0, 0, 0);
        }
        __builtin_amdgcn_s_setprio(0);

        float m01 = fmaxf(fmaxf(s[0][0], s[0][1]), fmaxf(s[0][2], s[0][3]));
        float m23 = fmaxf(fmaxf(s[1][0], s[1][1]), fmaxf(s[1][2], s[1][3]));
        float m45 = fmaxf(fmaxf(s[2][0], s[2][1]), fmaxf(s[2][2], s[2][3]));
        float m67 = fmaxf(fmaxf(s[3][0], s[3][1]), fmaxf(s[3][2], s[3][3]));
        float mt = fmaxf(fmaxf(m01, m23), fmaxf(m45, m67));
        mt = fmaxf(mt, __shfl_xor(mt, 16));
        mt = fmaxf(mt, __shfl_xor(mt, 32));
        // T13: skip rescale when tile max is within 8 of running max (P <= 2^8)
        if (!__all(mt - m_run <= 8.0f)) {
            float mn = fmaxf(m_run, mt);
            float c = exp2f(m_run - mn);
            m_run = mn;
            l_run *= c;
            #pragma unroll
            for (int t = 0; t < 4; ++t)
                #pragma unroll
                for (int r = 0; r < 4; ++r) acc[t][r] *= c;
        }
        float rs = 0.f;
        #pragma unroll
        for (int kt = 0; kt < 4; ++kt)
            #pragma unroll
            for (int r = 0; r < 4; ++r) {
                float p = exp2f(s[kt][r] - m_run);
                s[kt][r] = p;
                rs += p;
            }
        rs += __shfl_xor(rs, 16);
        rs += __shfl_xor(rs, 32);
        l_run += rs;

        #pragma unroll
        for (int kt = 0; kt < 4; ++kt) {
            u16x4 h;
            h[0] = (unsigned short)f2bf(s[kt][0]);
            h[1] = (unsigned short)f2bf(s[kt][1]);
            h[2] = (unsigned short)f2bf(s[kt][2]);
            h[3] = (unsigned short)f2bf(s[kt][3]);
            *(u16x4*)&P_lds[wid][l15][kt * 16 + lg * 4] = h;
        }

        __builtin_amdgcn_s_setprio(1);
        #pragma unroll
        for (int ps = 0; ps < 2; ++ps) {
            bf16x8 bp = *(const bf16x8*)&P_lds[wid][l15][ps * 32 + lg * 8];
            #pragma unroll
            for (int t = 0; t < 4; ++t) {
                const short* Vp = Vb + (t * 16 + l15) * 2048 + kv + ps * 32 + lg * 8;
                bf16x8 av = *(const bf16x8*)Vp;
                acc[t] = __builtin_amdgcn_mfma_f32_16x16x32_bf16(av, bp, acc[t], 0, 0, 0);
            }
        }
        __builtin_amdgcn_s_setprio(0);
    }

    if (lg == 0) {
        Mw[wid][l15] = m_run;
        Lw[wid][l15] = l_run;
    }
    __syncthreads();

    float mtot = Mw[0][l15];
    #pragma unroll
    for (int w = 1; w < 8; ++w) mtot = fmaxf(mtot, Mw[w][l15]);
    float fac = exp2f(m_run - mtot);
    #pragma unroll
    for (int t = 0; t < 4; ++t) {
        f32x4 v = acc[t];
        v[0] *= fac; v[1] *= fac; v[2] *= fac; v[3] *= fac;
        *(f32x4*)&accw[wid][l15][t * 16 + lg * 4] = v;
    }

    if (wid == 0 && lg == 0) {
        float L = 0.f;
        #pragma unroll
        for (int w = 0; w < 8; ++w)
            L += Lw[w][l15] * exp2f(Mw[w][l15] - mtot);
        Ltot[l15] = L;
        Mtot_s[l15] = mtot;
    }
    __syncthreads();

    int pidx = logical;
    #pragma unroll
    for (int j = 0; j < 2; ++j) {
        int o = tid + j * 512;
        int row = o >> 6, col = o & 63;
        float ssum = 0.f;
        #pragma unroll
        for (int w = 0; w < 8; ++w) ssum += accw[w][row][col];
        P_acc[(pidx * 16 + row) * 64 + col] = ssum;
    }
    if (tid < 16) {
        P_m[pidx * 16 + tid] = Mtot_s[tid];
        P_l[pidx * 16 + tid] = Ltot[tid];
    }
}

// ---------------- K4: combine the two kv-halves ----------------
__global__ __launch_bounds__(256) void attn_combine(const float* __restrict__ P_m,
                                                    const float* __restrict__ P_l,
                                                    const float* __restrict__ P_acc,
                                                    float* __restrict__ out) {
    int pair = blockIdx.x;
    int b_ = pair >> 7, qt = pair & 127;
    int p0 = pair * 2, p1 = pair * 2 + 1;
    #pragma unroll
    for (int j = 0; j < 4; ++j) {
        int o = threadIdx.x + j * 256;
        int row = o >> 6, col = o & 63;
        float m0 = P_m[p0 * 16 + row], m1 = P_m[p1 * 16 + row];
        float l0 = P_l[p0 * 16 + row], l1 = P_l[p1 * 16 + row];
        float m = fmaxf(m0, m1);
        float f0 = exp2f(m0 - m), f1 = exp2f(m1 - m);
        float L = l0 * f0 + l1 * f1;
        float a = P_acc[(p0 * 16 + row) * 64 + col] * f0
                + P_acc[(p1 * 16 + row) * 64 + col] * f1;
        out[(b_ * 2048 + qt * 16 + row) * 64 + col] = a / L;
    }
}

// ---------------- K3b: fallback attn (split x8, direct out, T13) ----------------
__global__ __launch_bounds__(512) void attn(const short* __restrict__ Q,
                                            const short* __restrict__ K,
                                            const short* __restrict__ Vt,
                                            float* __restrict__ out) {
    __shared__ float accw[8][16][68];
    __shared__ short P_lds[8][16][72];
    __shared__ float Mw[8][16];
    __shared__ float Lw[8][16];
    __shared__ float Ltot[16];

    int tid = threadIdx.x, wid = tid >> 6, lane = tid & 63;
    int l15 = lane & 15, lg = lane >> 4;
    int logical = (blockIdx.x & 7) * 64 + (blockIdx.x >> 3);
    int b_ = logical >> 7;
    int q0 = (logical & 127) * 16;
    const short* Kb = K + b_ * 2048 * 64;
    const short* Vb = Vt + b_ * 64 * 2048;

    const short* Qp = Q + (b_ * 2048 + q0 + l15) * 64 + lg * 8;
    bf16x8 bq0 = *(const bf16x8*)Qp;
    bf16x8 bq1 = *(const bf16x8*)(Qp + 32);

    f32x4 acc[4];
    #pragma unroll
    for (int t = 0; t < 4; ++t) acc[t] = (f32x4){0.f, 0.f, 0.f, 0.f};
    float m_run = -INFINITY, l_run = 0.f;

    int kv0 = wid * 256;
    for (int kv = kv0; kv < kv0 + 256; kv += 64) {
        f32x4 s[4];
        __builtin_amdgcn_s_setprio(1);
        #pragma unroll
        for (int kt = 0; kt < 4; ++kt) {
            const short* Kp = Kb + (kv + kt * 16 + l15) * 64 + lg * 8;
            bf16x8 ak0 = *(const bf16x8*)Kp;
            bf16x8 ak1 = *(const bf16x8*)(Kp + 32);
            f32x4 z = (f32x4){0.f, 0.f, 0.f, 0.f};
            z = __builtin_amdgcn_mfma_f32_16x16x32_bf16(ak0, bq0, z, 0, 0, 0);
            s[kt] = __builtin_amdgcn_mfma_f32_16x16x32_bf16(ak1, bq1, z, 0, 0, 0);
        }
        __builtin_amdgcn_s_setprio(0);

        float m01 = fmaxf(fmaxf(s[0][0], s[0][1]), fmaxf(s[0][2], s[0][3]));
        float m23 = fmaxf(fmaxf(s[1][0], s[1][1]), fmaxf(s[1][2], s[1][3]));
        float m45 = fmaxf(fmaxf(s[2][0], s[2][1]), fmaxf(s[2][2], s[2][3]));
        float m67 = fmaxf(fmaxf(s[3][0], s[3][1]), fmaxf(s[3][2], s[3][3]));
        float mt = fmaxf(fmaxf(m01, m23), fmaxf(m45, m67));
        mt = fmaxf(mt, __shfl_xor(mt, 16));
        mt = fmaxf(mt, __shfl_xor(mt, 32));
        if (!__all(mt - m_run <= 8.0f)) {
            float mn = fmaxf(m_run, mt);
            float c = exp2f(m_run - mn);
            m_run = mn;
            l_run *= c;
            #pragma unroll
            for (int t = 0; t < 4; ++t)
                #pragma unroll
                for (int r = 0; r < 4; ++r) acc[t][r] *= c;
        }
        float rs = 0.f;
        #pragma unroll
        for (int kt = 0; kt < 4; ++kt)
            #pragma unroll
            for (int r = 0; r < 4; ++r) {
                float p = exp2f(s[kt][r] - m_run);
                s[kt][r] = p;
                rs += p;
            }
        rs += __shfl_xor(rs, 16);
        rs += __shfl_xor(rs, 32);
        l_run += rs;

        #pragma unroll
        for (int kt = 0; kt < 4; ++kt) {
            u16x4 h;
            h[0] = (unsigned short)f2bf(s[kt][0]);
            h[1] = (unsigned short)f2bf(s[kt][1]);
            h[2] = (unsigned short)f2bf(s[kt][2]);
            h[3] = (unsigned short)f2bf(s[kt][3]);
            *(u16x4*)&P_lds[wid][l15][kt * 16 + lg * 4] = h;
        }

        __builtin_amdgcn_s_setprio(1);
        #pragma unroll
        for (int ps = 0; ps < 2; ++ps) {
            bf16x8 bp = *(const bf16x8*)&P_lds[wid][l15][ps * 32 + lg * 8];
            #pragma unroll
            for (int t = 0; t < 4; ++t) {
                const short* Vp = Vb + (t * 16 + l15) * 2048 + kv + ps * 32 + lg * 8;
                bf16x8 av = *(const bf16x8*)Vp;
                acc[t] = __builtin_amdgcn_mfma_f32_16x16x32_bf16(av, bp, acc[t], 0, 0, 0);
            }
        }
        __builtin_amdgcn_s_setprio(0);
    }

    if (lg == 0) {
        Mw[wid][l15] = m_run;
        Lw[wid][l15] = l_run;
    }
    __syncthreads();

    float mtot = Mw[0][l15];
    #pragma unroll
    for (int w = 1; w < 8; ++w) mtot = fmaxf(mtot, Mw[w][l15]);
    float fac = exp2f(m_run - mtot);
    #pragma unroll
    for (int t = 0; t < 4; ++t) {
        f32x4 v = acc[t];
        v[0] *= fac; v[1] *= fac; v[2] *= fac; v[3] *= fac;
        *(f32x4*)&accw[wid][l15][t * 16 + lg * 4] = v;
    }

    if (wid == 0 && lg == 0) {
        float L = 0.f;
        #pragma unroll
        for (int w = 0; w < 8; ++w)
            L += Lw[w][l15] * exp2f(Mw[w][l15] - mtot);
        Ltot[l15] = L;
    }
    __syncthreads();

    #pragma unroll
    for (int j = 0; j < 2; ++j) {
        int o = tid + j * 512;
        int row = o >> 6, col = o & 63;
        float ssum = 0.f;
        #pragma unroll
        for (int w = 0; w < 8; ++w) ssum += accw[w][row][col];
        out[(b_ * 2048 + q0 + row) * 64 + col] = ssum / Ltot[row];
    }
}

extern "C" void kernel_launch(void* const* d_in, const int* in_sizes, int n_in,
                              void* d_out, int out_size, void* d_ws, size_t ws_size,
                              hipStream_t stream) {
    const float* x  = (const float*)d_in[0];
    const float* Wq = (const float*)d_in[1];
    const float* Wk = (const float*)d_in[2];
    const float* Wv = (const float*)d_in[3];
    float* out = (float*)d_out;

    char* ws = (char*)d_ws;
    short* Wt = (short*)ws;                              // 393216 B
    short* Q  = (short*)(ws + 393216);                   // 1048576 B
    short* K  = (short*)(ws + 393216 + 1048576);         // 1048576 B
    short* Vt = (short*)(ws + 393216 + 2 * 1048576);     // 1048576 B  (3538944 total)
    float* P_m   = (float*)(ws + 3538944);               // 65536 B
    float* P_l   = (float*)(ws + 3538944 + 65536);       // 65536 B
    float* P_acc = (float*)(ws + 3538944 + 131072);      // 4194304 B
    const size_t WS_NEEDED = 3538944 + 131072 + 4194304; // 7864320

    hipLaunchKernelGGL(wtrans,   dim3(48),  dim3(256), 0, stream, Wq, Wk, Wv, Wt);
    hipLaunchKernelGGL(qkv_proj, dim3(512), dim3(256), 0, stream, x, Wt, Q, K, Vt);
    if (ws_size >= WS_NEEDED) {
        hipLaunchKernelGGL(attn16,       dim3(1024), dim3(512), 0, stream, Q, K, Vt, P_m, P_l, P_acc);
        hipLaunchKernelGGL(attn_combine, dim3(512),  dim3(256), 0, stream, P_m, P_l, P_acc, out);
    } else {
        hipLaunchKernelGGL(attn, dim3(512), dim3(512), 0, stream, Q, K, Vt, out);
    }
}

// Round 19
// 46.164 us; speedup vs baseline: 1.4030x; 1.3433x over previous
//
#include <hip/hip_runtime.h>
#include <hip/hip_bf16.h>

// Self-attention, fused QKV: x[4,2048,1024] f32, Wq/Wk/Wv[1024,64] f32 -> out[4,2048,64] f32
// bf16 MFMA (16x16x32), fp32 accumulation.
//   K1: wtrans  -- W -> Wt bf16 [192][1024], LDS tile-transpose.
//   K2: qkv_proj -- r16/r18 proven: 512 blocks x 4 waves, gload_lds 3-buffer
//       counted-vmcnt(5) pipeline, T1 XCD swizzle.
//   K3: attn32  -- flash attn, 32-QUERY tiles (halves K/V traffic vs 16q): each wave
//       serves 32 queries from one 256-key stream; K/V A-frags amortized over two
//       MFMA streams. Direct out (no combine kernel). P_lds/accw LDS union (69KB).
//       T13 defer-max + setprio kept.

typedef __attribute__((ext_vector_type(8))) short bf16x8;
typedef __attribute__((ext_vector_type(4))) float f32x4;
typedef __attribute__((ext_vector_type(4))) unsigned short u16x4;

#define QSCALE 0.1803368801111832f   // 0.125 * log2(e); logits land in exp2 domain

__device__ __forceinline__ short f2bf(float f) {
    union { float f; unsigned u; } v; v.f = f;
    unsigned r = v.u + 0x7FFF + ((v.u >> 16) & 1);   // round-to-nearest-even
    return (short)(r >> 16);
}

__device__ __forceinline__ void gload16(const void* src, void* dst) {
    __builtin_amdgcn_global_load_lds(
        (const __attribute__((address_space(1))) unsigned int*)src,
        (__attribute__((address_space(3))) unsigned int*)dst, 16, 0, 0);
}

// ---------------- K1: weight transpose + bf16 convert (coalesced) ----------------
__global__ __launch_bounds__(256) void wtrans(const float* __restrict__ Wq,
                                              const float* __restrict__ Wk,
                                              const float* __restrict__ Wv,
                                              short* __restrict__ Wt) {
    __shared__ short lds[64][66];
    int warr = blockIdx.x / 16;
    int d0 = (blockIdx.x % 16) * 64;
    const float* W = (warr == 0) ? Wq : (warr == 1) ? Wk : Wv;
    int rg = threadIdx.x >> 6;
    int c  = threadIdx.x & 63;
    #pragma unroll
    for (int p = 0; p < 16; ++p) {
        int d = p * 4 + rg;
        lds[d][c] = f2bf(W[(d0 + d) * 64 + c]);
    }
    __syncthreads();
    #pragma unroll
    for (int p = 0; p < 16; ++p) {
        int n = p * 4 + rg;
        Wt[(warr * 64 + n) * 1024 + d0 + c] = lds[c][n];
    }
}

// ---------------- K2: QKV projection (r16 pipeline + T1 swizzle) ----------------
__global__ __launch_bounds__(256) void qkv_proj(const float* __restrict__ x,
                                                const short* __restrict__ Wt,
                                                short* __restrict__ Q,
                                                short* __restrict__ K,
                                                short* __restrict__ Vt) {
    __shared__ char stage_lds[3][20480];
    __shared__ short Vlds[32][72];

    int tid = threadIdx.x;
    int wid = tid >> 6, lane = tid & 63;
    int l15 = lane & 15, lg = lane >> 4;
    int wr = wid >> 1, wn = wid & 1;
    int logical = (blockIdx.x & 7) * 64 + (blockIdx.x >> 3);
    int mbase = (logical >> 1) * 32;
    int nbase = (logical & 1) * 96;

    int a_soff[2];
    #pragma unroll
    for (int j = 0; j < 2; ++j) {
        int chunk = wid + j * 4;
        int row = chunk * 4 + (lane >> 4);
        int slot16 = lane & 15;
        int s32 = slot16 >> 1, h16 = slot16 & 1;
        int s32s = s32 ^ (row & 7);
        a_soff[j] = (mbase + row) * 1024 + s32s * 8 + h16 * 4;   // float offset
    }
    int b_soff[3];
    #pragma unroll
    for (int j = 0; j < 3; ++j) {
        int cb = wid + j * 4;
        int row = cb * 8 + (lane >> 3);
        int slot = lane & 7;
        int ss = slot ^ (row & 7);
        b_soff[j] = (nbase + row) * 1024 + ss * 8;               // short offset
    }

    f32x4 acc[3];
    #pragma unroll
    for (int f = 0; f < 3; ++f) acc[f] = (f32x4){0.f, 0.f, 0.f, 0.f};

    char* B0 = &stage_lds[0][0];
    char* B1 = &stage_lds[1][0];
    char* B2 = &stage_lds[2][0];

#define STAGE(step, base)                                                    \
    {                                                                        \
        int k0_ = (step) * 64;                                               \
        _Pragma("unroll")                                                    \
        for (int j = 0; j < 2; ++j)                                          \
            gload16(x + a_soff[j] + k0_, (base) + (wid + j * 4) * 1024);     \
        _Pragma("unroll")                                                    \
        for (int j = 0; j < 3; ++j)                                          \
            gload16(Wt + b_soff[j] + k0_, (base) + 8192 + (wid + j * 4) * 1024); \
    }

    STAGE(0, B0);
    STAGE(1, B1);
    asm volatile("s_waitcnt vmcnt(5)" ::: "memory");
    __builtin_amdgcn_s_barrier();
    __builtin_amdgcn_sched_barrier(0);

    for (int t = 0; t < 16; ++t) {
        int cm = t % 3;
        char* cbuf = (cm == 0) ? B0 : (cm == 1) ? B1 : B2;
        if (t + 2 < 16) {
            int nm = (t + 2) % 3;
            char* nbuf = (nm == 0) ? B0 : (nm == 1) ? B1 : B2;
            STAGE(t + 2, nbuf);
        }
        const char* Ab = cbuf;
        const char* Bb = cbuf + 8192;
        int arow = wr * 16 + l15;
        __builtin_amdgcn_s_setprio(1);
        #pragma unroll
        for (int h = 0; h < 2; ++h) {
            int s32s = (h * 4 + lg) ^ (arow & 7);
            const float4* ap = (const float4*)(Ab + arow * 256 + s32s * 32);
            float4 f0 = ap[0];
            float4 f1 = ap[1];
            bf16x8 a;
            a[0] = f2bf(f0.x); a[1] = f2bf(f0.y); a[2] = f2bf(f0.z); a[3] = f2bf(f0.w);
            a[4] = f2bf(f1.x); a[5] = f2bf(f1.y); a[6] = f2bf(f1.z); a[7] = f2bf(f1.w);
            #pragma unroll
            for (int f = 0; f < 3; ++f) {
                int brow = (wn * 3 + f) * 16 + l15;
                int ss = (h * 4 + lg) ^ (brow & 7);
                bf16x8 b = *(const bf16x8*)(Bb + brow * 128 + ss * 16);
                acc[f] = __builtin_amdgcn_mfma_f32_16x16x32_bf16(a, b, acc[f], 0, 0, 0);
            }
        }
        __builtin_amdgcn_s_setprio(0);
        if (t < 15) {
            if (t == 14) {
                asm volatile("s_waitcnt vmcnt(0)" ::: "memory");
            } else {
                asm volatile("s_waitcnt vmcnt(5)" ::: "memory");
            }
            __builtin_amdgcn_s_barrier();
            __builtin_amdgcn_sched_barrier(0);
        }
    }
#undef STAGE

    #pragma unroll
    for (int f = 0; f < 3; ++f) {
        int n = nbase + (wn * 3 + f) * 16 + l15;
        #pragma unroll
        for (int r = 0; r < 4; ++r) {
            int ml = wr * 16 + lg * 4 + r;
            int m = mbase + ml;
            float v = acc[f][r];
            if (n < 64) {
                Q[m * 64 + n] = f2bf(v * QSCALE);
            } else if (n < 128) {
                K[m * 64 + (n - 64)] = f2bf(v);
            } else {
                Vlds[ml][n - 128] = f2bf(v);
            }
        }
    }
    if (nbase == 96) {
        __syncthreads();
        int dk = tid >> 2;
        int m0 = (tid & 3) * 8;
        int b_ = mbase >> 11;
        int s_ = mbase & 2047;
        #pragma unroll
        for (int j = 0; j < 2; ++j) {
            u16x4 v;
            #pragma unroll
            for (int i = 0; i < 4; ++i) v[i] = (unsigned short)Vlds[m0 + j * 4 + i][dk];
            *(u16x4*)&Vt[(b_ * 64 + dk) * 2048 + s_ + m0 + j * 4] = v;
        }
    }
}

// ---------------- K3: flash attention, 32-query tiles, direct out ----------------
// grid = 4*64 = 256 blocks, 512 thr (8 waves). Wave: 32 queries x 256-key slice.
// P_lds (loop) and accw (epilogue) share one LDS union; barrier fences the reuse.
__global__ __launch_bounds__(512) void attn32(const short* __restrict__ Q,
                                              const short* __restrict__ K,
                                              const short* __restrict__ Vt,
                                              float* __restrict__ out) {
    __shared__ char ubuf[8][8704];   // per-wave: P [32][72]s (4608B) | accw [32][68]f (8704B)
    __shared__ float Mw[8][32];
    __shared__ float Lw[8][32];
    __shared__ float Ltot[32];

    int tid = threadIdx.x, wid = tid >> 6, lane = tid & 63;
    int l15 = lane & 15, lg = lane >> 4;
    // T1 chunked swizzle (256 = 8 XCDs x 32); logical: b(2) | qt(6)
    int logical = (blockIdx.x & 7) * 32 + (blockIdx.x >> 3);
    int b_ = logical >> 6;
    int q0 = (logical & 63) * 32;
    const short* Kb = K + b_ * 2048 * 64;
    const short* Vb = Vt + b_ * 64 * 2048;

    bf16x8 bq[2][2];
    #pragma unroll
    for (int qg = 0; qg < 2; ++qg) {
        const short* Qp = Q + (b_ * 2048 + q0 + qg * 16 + l15) * 64 + lg * 8;
        bq[qg][0] = *(const bf16x8*)Qp;
        bq[qg][1] = *(const bf16x8*)(Qp + 32);
    }

    short* P = (short*)&ubuf[wid][0];          // [32][72]

    f32x4 acc[2][4];
    #pragma unroll
    for (int qg = 0; qg < 2; ++qg)
        #pragma unroll
        for (int t = 0; t < 4; ++t) acc[qg][t] = (f32x4){0.f, 0.f, 0.f, 0.f};
    float m_run[2] = {-INFINITY, -INFINITY};
    float l_run[2] = {0.f, 0.f};

    int kv0 = wid * 256;
    for (int kv = kv0; kv < kv0 + 256; kv += 64) {
        // S^T = K Q for both q-groups; K A-frags loaded once
        f32x4 s[2][4];
        __builtin_amdgcn_s_setprio(1);
        #pragma unroll
        for (int kt = 0; kt < 4; ++kt) {
            const short* Kp = Kb + (kv + kt * 16 + l15) * 64 + lg * 8;
            bf16x8 ak0 = *(const bf16x8*)Kp;
            bf16x8 ak1 = *(const bf16x8*)(Kp + 32);
            f32x4 z0 = (f32x4){0.f, 0.f, 0.f, 0.f};
            z0 = __builtin_amdgcn_mfma_f32_16x16x32_bf16(ak0, bq[0][0], z0, 0, 0, 0);
            s[0][kt] = __builtin_amdgcn_mfma_f32_16x16x32_bf16(ak1, bq[0][1], z0, 0, 0, 0);
            f32x4 z1 = (f32x4){0.f, 0.f, 0.f, 0.f};
            z1 = __builtin_amdgcn_mfma_f32_16x16x32_bf16(ak0, bq[1][0], z1, 0, 0, 0);
            s[1][kt] = __builtin_amdgcn_mfma_f32_16x16x32_bf16(ak1, bq[1][1], z1, 0, 0, 0);
        }
        __builtin_amdgcn_s_setprio(0);

        // per-lane online softmax per q-group (T13 defer-max)
        #pragma unroll
        for (int qg = 0; qg < 2; ++qg) {
            float m01 = fmaxf(fmaxf(s[qg][0][0], s[qg][0][1]), fmaxf(s[qg][0][2], s[qg][0][3]));
            float m23 = fmaxf(fmaxf(s[qg][1][0], s[qg][1][1]), fmaxf(s[qg][1][2], s[qg][1][3]));
            float m45 = fmaxf(fmaxf(s[qg][2][0], s[qg][2][1]), fmaxf(s[qg][2][2], s[qg][2][3]));
            float m67 = fmaxf(fmaxf(s[qg][3][0], s[qg][3][1]), fmaxf(s[qg][3][2], s[qg][3][3]));
            float mt = fmaxf(fmaxf(m01, m23), fmaxf(m45, m67));
            mt = fmaxf(mt, __shfl_xor(mt, 16));
            mt = fmaxf(mt, __shfl_xor(mt, 32));
            if (!__all(mt - m_run[qg] <= 8.0f)) {
                float mn = fmaxf(m_run[qg], mt);
                float c = exp2f(m_run[qg] - mn);
                m_run[qg] = mn;
                l_run[qg] *= c;
                #pragma unroll
                for (int t = 0; t < 4; ++t)
                    #pragma unroll
                    for (int r = 0; r < 4; ++r) acc[qg][t][r] *= c;
            }
            float rs = 0.f;
            #pragma unroll
            for (int kt = 0; kt < 4; ++kt)
                #pragma unroll
                for (int r = 0; r < 4; ++r) {
                    float p = exp2f(s[qg][kt][r] - m_run[qg]);
                    s[qg][kt][r] = p;
                    rs += p;
                }
            rs += __shfl_xor(rs, 16);
            rs += __shfl_xor(rs, 32);
            l_run[qg] += rs;
        }

        // P -> per-wave private LDS, rows 0-15 qg0 (q=l15), rows 16-31 qg1
        #pragma unroll
        for (int qg = 0; qg < 2; ++qg)
            #pragma unroll
            for (int kt = 0; kt < 4; ++kt) {
                u16x4 h;
                h[0] = (unsigned short)f2bf(s[qg][kt][0]);
                h[1] = (unsigned short)f2bf(s[qg][kt][1]);
                h[2] = (unsigned short)f2bf(s[qg][kt][2]);
                h[3] = (unsigned short)f2bf(s[qg][kt][3]);
                *(u16x4*)&P[(qg * 16 + l15) * 72 + kt * 16 + lg * 4] = h;
            }

        // PV: V A-frags loaded once, feed both q-groups
        __builtin_amdgcn_s_setprio(1);
        #pragma unroll
        for (int ps = 0; ps < 2; ++ps) {
            bf16x8 bp0 = *(const bf16x8*)&P[l15 * 72 + ps * 32 + lg * 8];
            bf16x8 bp1 = *(const bf16x8*)&P[(16 + l15) * 72 + ps * 32 + lg * 8];
            #pragma unroll
            for (int t = 0; t < 4; ++t) {
                const short* Vp = Vb + (t * 16 + l15) * 2048 + kv + ps * 32 + lg * 8;
                bf16x8 av = *(const bf16x8*)Vp;
                acc[0][t] = __builtin_amdgcn_mfma_f32_16x16x32_bf16(av, bp0, acc[0][t], 0, 0, 0);
                acc[1][t] = __builtin_amdgcn_mfma_f32_16x16x32_bf16(av, bp1, acc[1][t], 0, 0, 0);
            }
        }
        __builtin_amdgcn_s_setprio(0);
    }

    // ---- deterministic cross-wave combine (8 disjoint key slices) ----
    if (lg == 0) {
        #pragma unroll
        for (int qg = 0; qg < 2; ++qg) {
            Mw[wid][qg * 16 + l15] = m_run[qg];
            Lw[wid][qg * 16 + l15] = l_run[qg];
        }
    }
    __syncthreads();   // all PV reads of P done; ubuf reusable as accw

    float* accw = (float*)&ubuf[wid][0];       // [32][68]
    #pragma unroll
    for (int qg = 0; qg < 2; ++qg) {
        int row = qg * 16 + l15;
        float m = Mw[0][row];
        #pragma unroll
        for (int w = 1; w < 8; ++w) m = fmaxf(m, Mw[w][row]);
        float fac = exp2f(m_run[qg] - m);
        #pragma unroll
        for (int t = 0; t < 4; ++t) {
            f32x4 v = acc[qg][t];
            v[0] *= fac; v[1] *= fac; v[2] *= fac; v[3] *= fac;
            *(f32x4*)&accw[row * 68 + t * 16 + lg * 4] = v;
        }
    }

    if (wid == 0 && lg == 0) {
        #pragma unroll
        for (int qg = 0; qg < 2; ++qg) {
            int row = qg * 16 + l15;
            float m = Mw[0][row];
            #pragma unroll
            for (int w = 1; w < 8; ++w) m = fmaxf(m, Mw[w][row]);
            float L = 0.f;
            #pragma unroll
            for (int w = 0; w < 8; ++w)
                L += Lw[w][row] * exp2f(Mw[w][row] - m);
            Ltot[row] = L;
        }
    }
    __syncthreads();

    #pragma unroll
    for (int j = 0; j < 4; ++j) {
        int o = tid + j * 512;
        int row = o >> 6, col = o & 63;
        float ssum = 0.f;
        #pragma unroll
        for (int w = 0; w < 8; ++w)
            ssum += ((const float*)&ubuf[w][0])[row * 68 + col];
        out[(b_ * 2048 + q0 + row) * 64 + col] = ssum / Ltot[row];
    }
}

extern "C" void kernel_launch(void* const* d_in, const int* in_sizes, int n_in,
                              void* d_out, int out_size, void* d_ws, size_t ws_size,
                              hipStream_t stream) {
    const float* x  = (const float*)d_in[0];
    const float* Wq = (const float*)d_in[1];
    const float* Wk = (const float*)d_in[2];
    const float* Wv = (const float*)d_in[3];
    float* out = (float*)d_out;

    char* ws = (char*)d_ws;
    short* Wt = (short*)ws;                              // 393216 B
    short* Q  = (short*)(ws + 393216);                   // 1048576 B
    short* K  = (short*)(ws + 393216 + 1048576);         // 1048576 B
    short* Vt = (short*)(ws + 393216 + 2 * 1048576);     // 1048576 B  (~3.4 MB total)

    hipLaunchKernelGGL(wtrans,   dim3(48),  dim3(256), 0, stream, Wq, Wk, Wv, Wt);
    hipLaunchKernelGGL(qkv_proj, dim3(512), dim3(256), 0, stream, x, Wt, Q, K, Vt);
    hipLaunchKernelGGL(attn32,   dim3(256), dim3(512), 0, stream, Q, K, Vt, out);
}